// Round 6
// baseline (236.897 us; speedup 1.0000x reference)
//
#include <hip/hip_runtime.h>
#include <math.h>

// Problem geometry (fixed by the reference): (4,16,4000,400) fp32
#define PLANE_ELEMS 1600000            // 4000*400 per (batch,shot) plane
#define NPLANES     64                 // 4*16
#define BPP         32                 // blocks per plane
#define NBLOCKS     (NPLANES * BPP)    // 2048
#define THREADS     256                // threads per block (4 waves)
#define N4          (PLANE_ELEMS / 4)  // 400000 float4 per plane
#define CHUNK       (N4 / BPP)         // 12500 float4 per block (contiguous)
#define UNROLL      4
#define NROUND      (CHUNK / (THREADS * UNROLL))  // 12 full rounds
#define TAILBASE    (NROUND * THREADS * UNROLL)   // 12288 (tail = 212)
#define COUNTER_OFF (NBLOCKS * 5)      // counter lives after the records (as int)

typedef float f32x4 __attribute__((ext_vector_type(4)));

// Fused: phase 1 = per-plane raw moments (f32 vector accumulators, NT loads,
// private ws record per block). Ticket: last block to finish runs phase 2
// (reads all 2048 records in a FIXED order -> bitwise-deterministic output).
// Counter is zeroed by a 4-byte memset before launch.
__global__ __launch_bounds__(THREADS)
void fwi_fused(const float* __restrict__ syn,
               const float* __restrict__ obs,
               double* __restrict__ ws,
               float* __restrict__ out)
{
    const int plane = blockIdx.x >> 5;      // / BPP
    const int bip   = blockIdx.x & (BPP - 1);

    const f32x4* s4 = reinterpret_cast<const f32x4*>(syn)
                      + (size_t)plane * N4 + (size_t)bip * CHUNK;
    const f32x4* o4 = reinterpret_cast<const f32x4*>(obs)
                      + (size_t)plane * N4 + (size_t)bip * CHUNK;

    f32x4 vs  = {0.f, 0.f, 0.f, 0.f};
    f32x4 vo  = {0.f, 0.f, 0.f, 0.f};
    f32x4 vss = {0.f, 0.f, 0.f, 0.f};
    f32x4 voo = {0.f, 0.f, 0.f, 0.f};
    f32x4 vso = {0.f, 0.f, 0.f, 0.f};

    int i = threadIdx.x;
    for (int r = 0; r < NROUND; ++r) {
        f32x4 a[UNROLL], b[UNROLL];
        #pragma unroll
        for (int u = 0; u < UNROLL; ++u) {
            a[u] = __builtin_nontemporal_load(s4 + i + u * THREADS);
            b[u] = __builtin_nontemporal_load(o4 + i + u * THREADS);
        }
        #pragma unroll
        for (int u = 0; u < UNROLL; ++u) {
            vs  += a[u];
            vo  += b[u];
            vss = __builtin_elementwise_fma(a[u], a[u], vss);
            voo = __builtin_elementwise_fma(b[u], b[u], voo);
            vso = __builtin_elementwise_fma(a[u], b[u], vso);
        }
        i += THREADS * UNROLL;
    }

    // Tail: CHUNK = 12500 = 12*1024 + 212; threads with tid < 212 do one more.
    i = TAILBASE + threadIdx.x;
    if (i < CHUNK) {
        f32x4 a = __builtin_nontemporal_load(s4 + i);
        f32x4 b = __builtin_nontemporal_load(o4 + i);
        vs  += a;
        vo  += b;
        vss = __builtin_elementwise_fma(a, a, vss);
        voo = __builtin_elementwise_fma(b, b, voo);
        vso = __builtin_elementwise_fma(a, b, vso);
    }

    // Horizontal reduce each vector accumulator in fp64
    double d_s  = ((double)vs.x  + (double)vs.y)  + ((double)vs.z  + (double)vs.w);
    double d_o  = ((double)vo.x  + (double)vo.y)  + ((double)vo.z  + (double)vo.w);
    double d_ss = ((double)vss.x + (double)vss.y) + ((double)vss.z + (double)vss.w);
    double d_oo = ((double)voo.x + (double)voo.y) + ((double)voo.z + (double)voo.w);
    double d_so = ((double)vso.x + (double)vso.y) + ((double)vso.z + (double)vso.w);

    // Wave(64)-level butterfly reduction in fp64
    #pragma unroll
    for (int off = 32; off > 0; off >>= 1) {
        d_s  += __shfl_down(d_s,  off);
        d_o  += __shfl_down(d_o,  off);
        d_ss += __shfl_down(d_ss, off);
        d_oo += __shfl_down(d_oo, off);
        d_so += __shfl_down(d_so, off);
    }

    __shared__ double sm1[THREADS / 64][5];
    const int wave = threadIdx.x >> 6;
    const int lane = threadIdx.x & 63;
    if (lane == 0) {
        sm1[wave][0] = d_s;  sm1[wave][1] = d_o;
        sm1[wave][2] = d_ss; sm1[wave][3] = d_oo; sm1[wave][4] = d_so;
    }
    __syncthreads();

    __shared__ int isLast;
    if (threadIdx.x == 0) {
        double t0 = 0, t1 = 0, t2 = 0, t3 = 0, t4 = 0;
        #pragma unroll
        for (int w = 0; w < THREADS / 64; ++w) {
            t0 += sm1[w][0]; t1 += sm1[w][1]; t2 += sm1[w][2];
            t3 += sm1[w][3]; t4 += sm1[w][4];
        }
        double* r = ws + (size_t)blockIdx.x * 5;
        r[0] = t0; r[1] = t1; r[2] = t2; r[3] = t3; r[4] = t4;

        // Publish record, then take a ticket (device-scope).
        __threadfence();
        int* counter = (int*)(ws + COUNTER_OFF);
        int old = atomicAdd(counter, 1);
        isLast = (old == NBLOCKS - 1);
    }
    __syncthreads();

    if (!isLast) return;
    __threadfence();   // acquire: all 2048 records now visible

    // ---- phase 2: this (last) block reduces everything ----
    const int t = threadIdx.x;
    const int p = t & 63;        // plane
    const int q = t >> 6;        // quarter 0..3 (8 records each)

    double acc0 = 0, acc1 = 0, acc2 = 0, acc3 = 0, acc4 = 0;
    #pragma unroll
    for (int b = 0; b < BPP / 4; ++b) {
        const double* r = ws + (size_t)((p * BPP) + (q * (BPP / 4)) + b) * 5;
        acc0 += r[0]; acc1 += r[1]; acc2 += r[2]; acc3 += r[3]; acc4 += r[4];
    }

    __shared__ double sm2[4][64][5];
    sm2[q][p][0] = acc0; sm2[q][p][1] = acc1; sm2[q][p][2] = acc2;
    sm2[q][p][3] = acc3; sm2[q][p][4] = acc4;
    __syncthreads();

    if (t < 64) {
        double Ss = 0, So = 0, Sss = 0, Soo = 0, Sso = 0;
        #pragma unroll
        for (int qq = 0; qq < 4; ++qq) {
            Ss  += sm2[qq][p][0];
            So  += sm2[qq][p][1];
            Sss += sm2[qq][p][2];
            Soo += sm2[qq][p][3];
            Sso += sm2[qq][p][4];
        }
        const double N = (double)PLANE_ELEMS;
        double cross = Sso - Ss * So / N;
        double Ep    = Sss - Ss * Ss / N;
        double Et    = Soo - So * So / N;
        double term  = cross / (sqrt(Et) * sqrt(Ep));

        #pragma unroll
        for (int off = 32; off > 0; off >>= 1)
            term += __shfl_down(term, off);

        if (p == 0)
            out[0] = (float)(-term);
    }
}

extern "C" void kernel_launch(void* const* d_in, const int* in_sizes, int n_in,
                              void* d_out, int out_size, void* d_ws, size_t ws_size,
                              hipStream_t stream)
{
    const float* syn = (const float*)d_in[0];
    const float* obs = (const float*)d_in[1];
    float* out       = (float*)d_out;
    double* ws       = (double*)d_ws;

    // Zero only the 4-byte ticket counter (graph-capture safe).
    hipMemsetAsync((void*)(ws + COUNTER_OFF), 0, sizeof(int), stream);

    fwi_fused<<<NBLOCKS, THREADS, 0, stream>>>(syn, obs, ws, out);
}

// Round 7
// 136.737 us; speedup vs baseline: 1.7325x; 1.7325x over previous
//
#include <hip/hip_runtime.h>
#include <math.h>

// Problem geometry (fixed by the reference): (4,16,4000,400) fp32
#define PLANE_ELEMS 1600000            // 4000*400 per (batch,shot) plane
#define NPLANES     64                 // 4*16
#define BPP         32                 // blocks per plane
#define THREADS     256                // threads per block (4 waves)
#define N4          (PLANE_ELEMS / 4)  // 400000 float4 per plane
#define CHUNK       (N4 / BPP)         // 12500 float4 per block (contiguous)
#define UNROLL      4
#define NROUND      (CHUNK / (THREADS * UNROLL))  // 12 full rounds
#define TAILBASE    (NROUND * THREADS * UNROLL)   // 12288 (tail = 212)

typedef float f32x4 __attribute__((ext_vector_type(4)));

// Stage 1: per-plane raw moments. Full-chunk f32 VECTOR accumulation
// (20 independent FMA chains), f64 only at the wave reduce. Nontemporal
// streaming loads. One private ws record per block (no atomics, no memset).
// ws layout: ws[(plane*BPP + bip)*5 + {0:S_s, 1:S_o, 2:S_ss, 3:S_oo, 4:S_so}]
__global__ __launch_bounds__(THREADS)
void fwi_partials(const float* __restrict__ syn,
                  const float* __restrict__ obs,
                  double* __restrict__ ws)
{
    const int plane = blockIdx.x >> 5;      // / BPP
    const int bip   = blockIdx.x & (BPP - 1);

    const f32x4* s4 = reinterpret_cast<const f32x4*>(syn)
                      + (size_t)plane * N4 + (size_t)bip * CHUNK;
    const f32x4* o4 = reinterpret_cast<const f32x4*>(obs)
                      + (size_t)plane * N4 + (size_t)bip * CHUNK;

    f32x4 vs  = {0.f, 0.f, 0.f, 0.f};
    f32x4 vo  = {0.f, 0.f, 0.f, 0.f};
    f32x4 vss = {0.f, 0.f, 0.f, 0.f};
    f32x4 voo = {0.f, 0.f, 0.f, 0.f};
    f32x4 vso = {0.f, 0.f, 0.f, 0.f};

    int i = threadIdx.x;
    for (int r = 0; r < NROUND; ++r) {
        f32x4 a[UNROLL], b[UNROLL];
        #pragma unroll
        for (int u = 0; u < UNROLL; ++u) {
            a[u] = __builtin_nontemporal_load(s4 + i + u * THREADS);
            b[u] = __builtin_nontemporal_load(o4 + i + u * THREADS);
        }
        #pragma unroll
        for (int u = 0; u < UNROLL; ++u) {
            vs  += a[u];
            vo  += b[u];
            vss = __builtin_elementwise_fma(a[u], a[u], vss);
            voo = __builtin_elementwise_fma(b[u], b[u], voo);
            vso = __builtin_elementwise_fma(a[u], b[u], vso);
        }
        i += THREADS * UNROLL;
    }

    // Tail: CHUNK = 12500 = 12*1024 + 212; threads with tid < 212 do one more.
    i = TAILBASE + threadIdx.x;
    if (i < CHUNK) {
        f32x4 a = __builtin_nontemporal_load(s4 + i);
        f32x4 b = __builtin_nontemporal_load(o4 + i);
        vs  += a;
        vo  += b;
        vss = __builtin_elementwise_fma(a, a, vss);
        voo = __builtin_elementwise_fma(b, b, voo);
        vso = __builtin_elementwise_fma(a, b, vso);
    }

    // Horizontal reduce each vector accumulator in fp64
    double d_s  = ((double)vs.x  + (double)vs.y)  + ((double)vs.z  + (double)vs.w);
    double d_o  = ((double)vo.x  + (double)vo.y)  + ((double)vo.z  + (double)vo.w);
    double d_ss = ((double)vss.x + (double)vss.y) + ((double)vss.z + (double)vss.w);
    double d_oo = ((double)voo.x + (double)voo.y) + ((double)voo.z + (double)voo.w);
    double d_so = ((double)vso.x + (double)vso.y) + ((double)vso.z + (double)vso.w);

    // Wave(64)-level butterfly reduction in fp64
    #pragma unroll
    for (int off = 32; off > 0; off >>= 1) {
        d_s  += __shfl_down(d_s,  off);
        d_o  += __shfl_down(d_o,  off);
        d_ss += __shfl_down(d_ss, off);
        d_oo += __shfl_down(d_oo, off);
        d_so += __shfl_down(d_so, off);
    }

    __shared__ double sm[THREADS / 64][5];
    const int wave = threadIdx.x >> 6;
    const int lane = threadIdx.x & 63;
    if (lane == 0) {
        sm[wave][0] = d_s;  sm[wave][1] = d_o;
        sm[wave][2] = d_ss; sm[wave][3] = d_oo; sm[wave][4] = d_so;
    }
    __syncthreads();

    if (threadIdx.x == 0) {
        double t0 = 0, t1 = 0, t2 = 0, t3 = 0, t4 = 0;
        #pragma unroll
        for (int w = 0; w < THREADS / 64; ++w) {
            t0 += sm[w][0]; t1 += sm[w][1]; t2 += sm[w][2];
            t3 += sm[w][3]; t4 += sm[w][4];
        }
        double* r = ws + (size_t)blockIdx.x * 5;
        r[0] = t0; r[1] = t1; r[2] = t2; r[3] = t3; r[4] = t4;
    }
}

// Stage 2: one block of 256 threads reduces 64 planes x 32 partial records,
// computes the closed-form zero-mean correlation per plane, sums across planes.
__global__ __launch_bounds__(256)
void fwi_final(const double* __restrict__ ws, float* __restrict__ out)
{
    const int t = threadIdx.x;
    const int p = t & 63;        // plane
    const int q = t >> 6;        // quarter 0..3 (8 records each)

    double acc0 = 0, acc1 = 0, acc2 = 0, acc3 = 0, acc4 = 0;
    #pragma unroll
    for (int b = 0; b < BPP / 4; ++b) {
        const double* r = ws + (size_t)((p * BPP) + (q * (BPP / 4)) + b) * 5;
        acc0 += r[0]; acc1 += r[1]; acc2 += r[2]; acc3 += r[3]; acc4 += r[4];
    }

    __shared__ double sm[4][64][5];
    sm[q][p][0] = acc0; sm[q][p][1] = acc1; sm[q][p][2] = acc2;
    sm[q][p][3] = acc3; sm[q][p][4] = acc4;
    __syncthreads();

    if (t < 64) {
        double Ss = 0, So = 0, Sss = 0, Soo = 0, Sso = 0;
        #pragma unroll
        for (int qq = 0; qq < 4; ++qq) {
            Ss  += sm[qq][p][0];
            So  += sm[qq][p][1];
            Sss += sm[qq][p][2];
            Soo += sm[qq][p][3];
            Sso += sm[qq][p][4];
        }
        const double N = (double)PLANE_ELEMS;
        double cross = Sso - Ss * So / N;
        double Ep    = Sss - Ss * Ss / N;
        double Et    = Soo - So * So / N;
        double term  = cross / (sqrt(Et) * sqrt(Ep));

        #pragma unroll
        for (int off = 32; off > 0; off >>= 1)
            term += __shfl_down(term, off);

        if (p == 0)
            out[0] = (float)(-term);
    }
}

extern "C" void kernel_launch(void* const* d_in, const int* in_sizes, int n_in,
                              void* d_out, int out_size, void* d_ws, size_t ws_size,
                              hipStream_t stream)
{
    const float* syn = (const float*)d_in[0];
    const float* obs = (const float*)d_in[1];
    float* out       = (float*)d_out;
    double* ws       = (double*)d_ws;

    fwi_partials<<<NPLANES * BPP, THREADS, 0, stream>>>(syn, obs, ws);
    fwi_final<<<1, 256, 0, stream>>>(ws, out);
}